// Round 4
// baseline (201.741 us; speedup 1.0000x reference)
//
#include <hip/hip_runtime.h>

// VectorQuantizer: latents (16,128,64,64) f32, codebook (1024,128) f32.
// out[b,d,h,w] = codebook[argmin_k fl(fl(x2 - 2*dot(x,e_k)) + e2_k)][d]
//
// MFMA bf16 scoring + exact fp32 rescue:
//  phase 1: 16x16x32 bf16 MFMA scores (fp32 acc) -> per-px min in the
//           x2-free domain s' = fl(e2_k - 2*C_k)  (translation-invariant
//           argmin; composition rounding folded into slop).
//  phase 2: recompute s'; candidates = { k : s' <= min' + 2*M[px] },
//           M = 2e-4*sqrt(x2) + 2.5e-4  (validated R3: passed 3.8e-6).
//  rescue:  exact fp32 serial ascending-d fmaf chain on ~2 cands/px;
//           lex (t3,k) u64 atomicMin keeps np first-index tie-break.
//
// Round-7 (latency round -- occupancy exonerated by R2/R3 cross-check):
//  - B+e2 register dual-buffer prefetch (unroll-2 rotation): the 32 c-iters
//    were serial load->wait->MFMA (cbbf evicted from 4MB L2 by the 64MB
//    latents/out stream -> L3 latency exposed every iter). R0's spill was
//    the (256,4) floor, not the pattern; plain bounds, ~140 VGPR peak.
//  - rescue + x2 back to fp32 xl[d][px] in LDS (exact R2 code, bank-free;
//    same values/order as R3's global reads -> bit-identical results).
//    R3's rescue did 128 scattered 16KB-stride global loads per candidate.
//  - LDS aliasing: xbf (16KB) dead after A-build barrier; cand+bfminw
//    union onto it. 32K(xl)+16K(union)+1K = 50.2KB -> 3 blocks/CU.
//    CAND_CAP 4096 for free. Barrier after A-build doubles as x2s-ready.
//  - keep: xbf swizzled A-build, 1-fma epilogue, R3 prep, nt out stores.

typedef __attribute__((ext_vector_type(8))) short short8;
typedef __attribute__((ext_vector_type(4))) float f32x4;

#define VQ_D 128
#define VQ_K 1024
#define VQ_HW 4096
#define CAND_CAP 4096

__device__ inline unsigned short f2bf(float f) {   // RNE fp32->bf16
    unsigned u = __float_as_uint(f);
    return (unsigned short)((u + 0x7FFFu + ((u >> 16) & 1u)) >> 16);
}

__global__ __launch_bounds__(256)
void vq_prep_kernel(const float* __restrict__ cb, unsigned short* __restrict__ cbbf,
                    float* __restrict__ e2) {
    __shared__ __align__(16) float rows[32][132];
    const int tid = threadIdx.x;
    const int k0  = blockIdx.x << 5;                 // 32 codes/block, grid=32
    const float4* s4 = (const float4*)(cb + (size_t)k0 * VQ_D);
    ushort4* d4 = (ushort4*)(cbbf + (size_t)k0 * VQ_D);
    #pragma unroll
    for (int i = 0; i < 4; ++i) {                    // 1024 float4 per block
        const int idx = i * 256 + tid;               // coalesced
        const float4 v = s4[idx];
        const int r  = idx >> 5;
        const int c4 = (idx & 31) << 2;
        *(float4*)(&rows[r][c4]) = v;
        ushort4 p;
        p.x = f2bf(v.x); p.y = f2bf(v.y); p.z = f2bf(v.z); p.w = f2bf(v.w);
        d4[idx] = p;
    }
    __syncthreads();
    if (tid < 32) {                                  // serial chain, same order
        float s = 0.f;
        #pragma unroll
        for (int d = 0; d < VQ_D; ++d) {
            const float v = rows[tid][d];
            s = fmaf(v, v, s);
        }
        e2[k0 + tid] = s;
    }
}

// prefetch helpers ----------------------------------------------------------
#define VQ_LDB(Bdst, ev, c_)                                                     \
    {                                                                            \
        _Pragma("unroll")                                                        \
        for (int t = 0; t < 4; ++t)                                              \
            Bdst[t] = *(const short8*)(bbase + (size_t)(c_) * 16 * VQ_D + t * 32); \
        ev = e2g[(c_) * 16];                                                     \
    }

#define VQ_MFMA(Bv)                                                              \
    f32x4 Cm[4] = {{0.f,0.f,0.f,0.f},{0.f,0.f,0.f,0.f},                          \
                   {0.f,0.f,0.f,0.f},{0.f,0.f,0.f,0.f}};                         \
    _Pragma("unroll")                                                            \
    for (int t = 0; t < 4; ++t)                                                  \
        _Pragma("unroll")                                                        \
        for (int p = 0; p < 4; ++p)                                              \
            Cm[p] = __builtin_amdgcn_mfma_f32_16x16x32_bf16(                     \
                        A[p * 4 + t], Bv[t], Cm[p], 0, 0, 0);

#define VQ_EP1(Bv, ev)                                                           \
    {                                                                            \
        VQ_MFMA(Bv)                                                              \
        _Pragma("unroll")                                                        \
        for (int p = 0; p < 4; ++p)                                              \
            _Pragma("unroll")                                                    \
            for (int r = 0; r < 4; ++r) {                                        \
                const float s = fmaf(-2.0f, Cm[p][r], ev);                       \
                bmin[p * 4 + r] = fminf(bmin[p * 4 + r], s);                     \
            }                                                                    \
    }

#define VQ_EP2(Bv, ev, c_)                                                       \
    {                                                                            \
        VQ_MFMA(Bv)                                                              \
        _Pragma("unroll")                                                        \
        for (int p = 0; p < 4; ++p)                                              \
            _Pragma("unroll")                                                    \
            for (int r = 0; r < 4; ++r) {                                        \
                const float s = fmaf(-2.0f, Cm[p][r], ev);                       \
                if (s <= thr[p * 4 + r]) {                                       \
                    const int idx = atomicAdd(&ncand, 1);                        \
                    if (idx < CAND_CAP) {                                        \
                        const int px   = p * 16 + quad * 4 + r;                  \
                        const int code = wave * 256 + (c_) * 16 + mm;            \
                        cand[idx] = ((unsigned)px << 16) | (unsigned)code;       \
                    }                                                            \
                }                                                                \
            }                                                                    \
    }

__global__ __launch_bounds__(256)
void vq_main_kernel(const float* __restrict__ latents,
                    const float* __restrict__ cb,
                    const unsigned short* __restrict__ cbbf,
                    const float* __restrict__ e2,
                    float* __restrict__ out) {
    __shared__ __align__(16) float xl[VQ_D * 64];            // [d][px] fp32 32 KB
    // bf16 x tile [px][d], 16B slots XOR-swizzled by px&15; DEAD after the
    // A-build barrier -> cand and bfminw alias its storage (16 KB).
    __shared__ __align__(16) unsigned short xbf[64 * 128];   // 16 KB
    __shared__ float x2s[64];
    __shared__ float threshs[64];
    __shared__ unsigned long long fkey[64];
    __shared__ int ncand;
    unsigned int* cand = (unsigned int*)xbf;                 // [CAND_CAP] 16 KB
    float (*bfminw)[64] = (float (*)[64])xbf;                // phase-1 only

    const int tid  = threadIdx.x;
    const int lane = tid & 63;
    const int wave = __builtin_amdgcn_readfirstlane(tid >> 6);
    const int quad = lane >> 4;
    const int mm   = lane & 15;
    const int blk  = blockIdx.x;
    const int b    = blk >> 6;
    const int hw0  = (blk & 63) << 6;

    const float* xg = latents + (size_t)b * VQ_D * VQ_HW + hw0;

    // ---- stage: coalesced float4 loads -> fp32 xl (float4 writes) + bf16 xbf
    {
        const int px4 = (tid & 15) << 2;
        const int db  = (tid >> 4) << 3;
        #pragma unroll
        for (int dp = 0; dp < 4; ++dp) {             // d-pairs
            const int d0 = db + dp * 2;
            const float4 va = *(const float4*)(xg + (size_t)d0 * VQ_HW + px4);
            const float4 vb = *(const float4*)(xg + (size_t)(d0 + 1) * VQ_HW + px4);
            *(float4*)(xl + d0 * 64 + px4)       = va;
            *(float4*)(xl + (d0 + 1) * 64 + px4) = vb;
            const float* fa = (const float*)&va;
            const float* fb = (const float*)&vb;
            #pragma unroll
            for (int i = 0; i < 4; ++i) {
                const int px = px4 + i;
                const unsigned lo = f2bf(fa[i]);
                const unsigned hi = f2bf(fb[i]);
                const int slot = (d0 >> 3) ^ (px & 15);
                *(unsigned*)((char*)xbf + px * 256 + slot * 16 + (d0 & 7) * 2) =
                    lo | (hi << 16);
            }
        }
    }
    if (tid == 0) ncand = 0;
    if (tid < 64) fkey[tid] = ~0ULL;
    __syncthreads();   // xl + xbf staged

    // ---- A fragments (64 VGPR): px=p*16+mm, d=t*32+quad*8+j, conflict-free
    short8 A[16];
    #pragma unroll
    for (int p = 0; p < 4; ++p) {
        const int px = p * 16 + mm;
        #pragma unroll
        for (int t = 0; t < 4; ++t) {
            const int slot = (t * 4 + quad) ^ mm;    // px&15 == mm
            A[p * 4 + t] = *(const short8*)((const char*)xbf + px * 256 + slot * 16);
        }
    }

    // x2 per px: serial ascending-d chain from xl (identical values/order)
    if (tid < 64) {
        float s = 0.f;
        #pragma unroll
        for (int d = 0; d < VQ_D; ++d) {
            const float v = xl[d * 64 + tid];
            s = fmaf(v, v, s);
        }
        x2s[tid] = s;
    }
    __syncthreads();   // xbf now DEAD (A in regs); x2s ready; aliasing legal

    const float* e2g = e2 + wave * 256 + mm;   // e2 for code group c: e2g[c*16]
    const unsigned short* bbase = cbbf + (size_t)(wave * 256 + mm) * VQ_D + quad * 8;

    // ---- phase 1: x2-free score min, B+e2 dual-buffer prefetch ----
    float bmin[16];
    #pragma unroll
    for (int i = 0; i < 16; ++i) bmin[i] = 1e30f;

    {
        short8 B0[4], B1[4];
        float e0, e1;
        VQ_LDB(B0, e0, 0)
        #pragma unroll 1
        for (int cc = 0; cc < 8; ++cc) {
            const int c0 = cc * 2;
            VQ_LDB(B1, e1, c0 + 1)
            VQ_EP1(B0, e0)
            if (cc < 7) VQ_LDB(B0, e0, c0 + 2)
            VQ_EP1(B1, e1)
        }
    }

    // reduce min across the 16 lanes of each quad-group (code dimension)
    #pragma unroll
    for (int i = 0; i < 16; ++i) {
        float v = bmin[i];
        v = fminf(v, __shfl_xor(v, 1));
        v = fminf(v, __shfl_xor(v, 2));
        v = fminf(v, __shfl_xor(v, 4));
        v = fminf(v, __shfl_xor(v, 8));
        bmin[i] = v;
    }
    if (mm == 0) {
        #pragma unroll
        for (int p = 0; p < 4; ++p)
            #pragma unroll
            for (int r = 0; r < 4; ++r)
                bfminw[wave][p * 16 + quad * 4 + r] = bmin[p * 4 + r];
    }
    __syncthreads();
    if (tid < 64) {
        const float mn = fminf(fminf(bfminw[0][tid], bfminw[1][tid]),
                               fminf(bfminw[2][tid], bfminw[3][tid]));
        const float M = 2.0e-4f * sqrtf(x2s[tid]) + 2.5e-4f;
        threshs[tid] = mn + 2.0f * M;
    }
    __syncthreads();   // bfminw dead; cand writes may begin

    float thr[16];
    #pragma unroll
    for (int p = 0; p < 4; ++p)
        #pragma unroll
        for (int r = 0; r < 4; ++r)
            thr[p * 4 + r] = threshs[p * 16 + quad * 4 + r];

    // ---- phase 2: recompute s', collect candidates (prefetched) ----
    {
        short8 B0[4], B1[4];
        float e0, e1;
        VQ_LDB(B0, e0, 0)
        #pragma unroll 1
        for (int cc = 0; cc < 8; ++cc) {
            const int c0 = cc * 2;
            VQ_LDB(B1, e1, c0 + 1)
            VQ_EP2(B0, e0, c0)
            if (cc < 7) VQ_LDB(B0, e0, c0 + 2)
            VQ_EP2(B1, e1, c0 + 1)
        }
    }
    __syncthreads();

    // ---- rescue: exact fp32 serial chain on candidates, one per lane.
    //      xl reads are bank-free ([d][px]: lanes hit px mod 32 spread).
    const int nc = ncand < CAND_CAP ? ncand : CAND_CAP;
    for (int i = tid; i < nc; i += 256) {
        const unsigned pc = cand[i];
        const int px = (int)(pc >> 16);
        const int k  = (int)(pc & 0xFFFFu);
        const float* crow = cb + (size_t)k * VQ_D;
        float dot = 0.f;
        #pragma unroll
        for (int q = 0; q < 32; ++q) {
            const float4 cv = *(const float4*)(crow + q * 4);
            dot = fmaf(xl[(q * 4 + 0) * 64 + px], cv.x, dot);
            dot = fmaf(xl[(q * 4 + 1) * 64 + px], cv.y, dot);
            dot = fmaf(xl[(q * 4 + 2) * 64 + px], cv.z, dot);
            dot = fmaf(xl[(q * 4 + 3) * 64 + px], cv.w, dot);
        }
        const float t3 = (x2s[px] - 2.0f * dot) + e2[k];
        const unsigned long long key =
            ((unsigned long long)__float_as_uint(t3) << 32) | (unsigned)k;
        atomicMin(&fkey[px], key);
    }
    __syncthreads();

    // ---- writeback: vectorized codebook reads, nontemporal out stores ----
    {
        const int px = tid & 63;
        const int dh = tid >> 6;
        const int fb = (int)(fkey[px] & 0xFFFFFFFFULL);
        const float* crow = cb + (size_t)fb * VQ_D + dh * 32;
        float* og = out + (size_t)b * VQ_D * VQ_HW + hw0;
        #pragma unroll
        for (int j = 0; j < 8; ++j) {
            const float4 cv = *(const float4*)(crow + j * 4);
            const int d = dh * 32 + j * 4;
            __builtin_nontemporal_store(cv.x, &og[(size_t)(d + 0) * VQ_HW + px]);
            __builtin_nontemporal_store(cv.y, &og[(size_t)(d + 1) * VQ_HW + px]);
            __builtin_nontemporal_store(cv.z, &og[(size_t)(d + 2) * VQ_HW + px]);
            __builtin_nontemporal_store(cv.w, &og[(size_t)(d + 3) * VQ_HW + px]);
        }
    }
}

extern "C" void kernel_launch(void* const* d_in, const int* in_sizes, int n_in,
                              void* d_out, int out_size, void* d_ws, size_t ws_size,
                              hipStream_t stream) {
    const float* latents = (const float*)d_in[0];
    const float* cb      = (const float*)d_in[1];
    unsigned short* cbbf = (unsigned short*)d_ws;              // 256 KB
    float* e2            = (float*)((char*)d_ws + 262144);     // 4 KB
    float* out           = (float*)d_out;

    vq_prep_kernel<<<dim3(32), dim3(256), 0, stream>>>(cb, cbbf, e2);
    vq_main_kernel<<<dim3(1024), dim3(256), 0, stream>>>(latents, cb, cbbf, e2, out);
}

// Round 5
// 192.419 us; speedup vs baseline: 1.0484x; 1.0484x over previous
//
#include <hip/hip_runtime.h>

// VectorQuantizer: latents (16,128,64,64) f32, codebook (1024,128) f32.
// out[b,d,h,w] = codebook[argmin_k fl(fl(x2 - 2*dot(x,e_k)) + e2_k)][d]
//
// MFMA bf16 scoring + exact fp32 rescue:
//  phase 1: 16x16x32 bf16 MFMA scores (fp32 acc) -> per-px min in the
//           x2-free domain s' = fl(e2_k - 2*C_k)  (translation-invariant
//           argmin; composition rounding folded into slop).
//  phase 2: recompute s'; candidates = { k : s' <= min' + 2*M[px] },
//           M = 2e-4*sqrt(x2) + 2.5e-4  (validated R3/R4: absmax 3.8e-6).
//  rescue:  exact fp32 serial ascending-d fmaf chain on ~2 cands/px;
//           lex (t3,k) u64 atomicMin keeps np first-index tie-break.
//
// Round-8 (async round). Cross-round matrix: occupancy up (R3) and down
// (R4) both lose; register B-prefetch (R4) loses via VGPR 144 -> 11% occ.
// All pipes <25% busy every round => exposed B-load latency in the c-loop.
// Fix with the only zero-VGPR prefetch: wave-private double-buffered LDS
// B-tiles via global_load_lds (m97 transform, +69% on the GEMM ladder):
//  - per c-iter each wave needs 16 codes x 256B = 4KB of cbbf. Prefetch
//    tile c+1 (4 async 1KB global_load_lds, dest = uniform base+lane*16)
//    while MFMA+epilogue run on tile c. NO barrier in the loop (buffers
//    are wave-private) -> no vmcnt(0)+s_barrier drain problem.
//  - consume via 4 lane-contiguous ds_read_b128 after an explicit
//    s_waitcnt vmcnt(0) + sched_barrier(0) (rule-18 discipline).
//  - base = R3 (64 VGPR): xbf swizzled A-build, 1-fma epilogue, x2 and
//    rescue from global (L2-hot 32KB block footprint), cand aliases xbf.
//  - LDS: 16K xbf + 32K Bdbuf + 1K misc = 50K -> 3 blocks/CU.

typedef __attribute__((ext_vector_type(8))) short short8;
typedef __attribute__((ext_vector_type(4))) float f32x4;

#define VQ_D 128
#define VQ_K 1024
#define VQ_HW 4096
#define CAND_CAP 4096

__device__ inline unsigned short f2bf(float f) {   // RNE fp32->bf16
    unsigned u = __float_as_uint(f);
    return (unsigned short)((u + 0x7FFFu + ((u >> 16) & 1u)) >> 16);
}

__device__ inline void vq_gl16(const void* g, void* l) {   // async 16B/lane -> LDS
    __builtin_amdgcn_global_load_lds(
        (const __attribute__((address_space(1))) unsigned int*)g,
        (__attribute__((address_space(3))) unsigned int*)l, 16, 0, 0);
}

__global__ __launch_bounds__(256)
void vq_prep_kernel(const float* __restrict__ cb, unsigned short* __restrict__ cbbf,
                    float* __restrict__ e2) {
    __shared__ __align__(16) float rows[32][132];
    const int tid = threadIdx.x;
    const int k0  = blockIdx.x << 5;                 // 32 codes/block, grid=32
    const float4* s4 = (const float4*)(cb + (size_t)k0 * VQ_D);
    ushort4* d4 = (ushort4*)(cbbf + (size_t)k0 * VQ_D);
    #pragma unroll
    for (int i = 0; i < 4; ++i) {                    // 1024 float4 per block
        const int idx = i * 256 + tid;               // coalesced
        const float4 v = s4[idx];
        const int r  = idx >> 5;
        const int c4 = (idx & 31) << 2;
        *(float4*)(&rows[r][c4]) = v;
        ushort4 p;
        p.x = f2bf(v.x); p.y = f2bf(v.y); p.z = f2bf(v.z); p.w = f2bf(v.w);
        d4[idx] = p;
    }
    __syncthreads();
    if (tid < 32) {                                  // serial chain, same order
        float s = 0.f;
        #pragma unroll
        for (int d = 0; d < VQ_D; ++d) {
            const float v = rows[tid][d];
            s = fmaf(v, v, s);
        }
        e2[k0 + tid] = s;
    }
}

// ---- pipeline helpers ------------------------------------------------------
// Prefetch B-tile for code-group c_ into wave-private buffer s_ (4 x 1KB).
// Per-lane global src = row (wave*256 + c*16 + mm), bytes t*64 + quad*16;
// LDS dest = base + t*1024 + lane*16 (HW scatter).
#define VQ_PF(s_, c_)                                                            \
    {                                                                            \
        const unsigned short* gsrc = gB + (size_t)(c_) * 16 * VQ_D;              \
        char* ld = Bw + (s_) * 4096;                                             \
        vq_gl16(gsrc,      ld);                                                  \
        vq_gl16(gsrc + 32, ld + 1024);                                           \
        vq_gl16(gsrc + 64, ld + 2048);                                           \
        vq_gl16(gsrc + 96, ld + 3072);                                           \
    }

#define VQ_RDB(Bv, s_)                                                           \
    {                                                                            \
        const char* ls = Bw + (s_) * 4096 + lane * 16;                           \
        Bv[0] = *(const short8*)(ls);                                            \
        Bv[1] = *(const short8*)(ls + 1024);                                     \
        Bv[2] = *(const short8*)(ls + 2048);                                     \
        Bv[3] = *(const short8*)(ls + 3072);                                     \
    }

#define VQ_MFMA(Bv)                                                              \
    f32x4 Cm[4] = {{0.f,0.f,0.f,0.f},{0.f,0.f,0.f,0.f},                          \
                   {0.f,0.f,0.f,0.f},{0.f,0.f,0.f,0.f}};                         \
    _Pragma("unroll")                                                            \
    for (int t = 0; t < 4; ++t)                                                  \
        _Pragma("unroll")                                                        \
        for (int p = 0; p < 4; ++p)                                              \
            Cm[p] = __builtin_amdgcn_mfma_f32_16x16x32_bf16(                     \
                        A[p * 4 + t], Bv[t], Cm[p], 0, 0, 0);

__global__ __launch_bounds__(256)
void vq_main_kernel(const float* __restrict__ latents,
                    const float* __restrict__ cb,
                    const unsigned short* __restrict__ cbbf,
                    const float* __restrict__ e2,
                    float* __restrict__ out) {
    // bf16 x tile [px][d], 16B slots XOR-swizzled by px&15; DEAD after the
    // A-build barrier -> cand (and bfminw) alias its 16KB.
    __shared__ __align__(16) unsigned short xbf[64 * 128];   // 16 KB
    __shared__ __align__(16) char Blds[4][2][4096];          // 32 KB B dbuf
    __shared__ float x2s[64];
    __shared__ float threshs[64];
    __shared__ unsigned long long fkey[64];
    __shared__ int ncand;
    unsigned int* cand = (unsigned int*)xbf;                 // [4096] 16 KB
    float (*bfminw)[64] = (float (*)[64])xbf;                // phase-1 reduce only

    const int tid  = threadIdx.x;
    const int lane = tid & 63;
    const int wave = __builtin_amdgcn_readfirstlane(tid >> 6);
    const int quad = lane >> 4;
    const int mm   = lane & 15;
    const int blk  = blockIdx.x;
    const int b    = blk >> 6;
    const int hw0  = (blk & 63) << 6;

    const float* xg = latents + (size_t)b * VQ_D * VQ_HW + hw0;

    // ---- stage x tile: coalesced float4 loads, f2bf once, swizzled b32 writes
    {
        const int px4 = (tid & 15) << 2;
        const int db  = (tid >> 4) << 3;
        #pragma unroll
        for (int dp = 0; dp < 4; ++dp) {             // d-pairs
            const int d0 = db + dp * 2;
            const float4 va = *(const float4*)(xg + (size_t)d0 * VQ_HW + px4);
            const float4 vb = *(const float4*)(xg + (size_t)(d0 + 1) * VQ_HW + px4);
            const float* fa = (const float*)&va;
            const float* fb = (const float*)&vb;
            #pragma unroll
            for (int i = 0; i < 4; ++i) {
                const int px = px4 + i;
                const unsigned lo = f2bf(fa[i]);
                const unsigned hi = f2bf(fb[i]);
                const int slot = (d0 >> 3) ^ (px & 15);
                *(unsigned*)((char*)xbf + px * 256 + slot * 16 + (d0 & 7) * 2) =
                    lo | (hi << 16);
            }
        }
    }
    if (tid == 0) ncand = 0;
    if (tid < 64) fkey[tid] = ~0ULL;

    // x2 per px: serial ascending-d chain from GLOBAL (identical values/order;
    // lines are L2-hot from the staging reads)
    if (tid < 64) {
        float s = 0.f;
        #pragma unroll
        for (int d = 0; d < VQ_D; ++d) {
            const float v = xg[(size_t)d * VQ_HW + tid];
            s = fmaf(v, v, s);
        }
        x2s[tid] = s;
    }
    __syncthreads();   // xbf + x2s staged

    // ---- A fragments (64 VGPR): px=p*16+mm, d=t*32+quad*8+j (swizzle-free)
    short8 A[16];
    #pragma unroll
    for (int p = 0; p < 4; ++p) {
        const int px = p * 16 + mm;
        #pragma unroll
        for (int t = 0; t < 4; ++t) {
            const int slot = (t * 4 + quad) ^ mm;    // px&15 == mm
            A[p * 4 + t] = *(const short8*)((const char*)xbf + px * 256 + slot * 16);
        }
    }
    __syncthreads();   // xbf DEAD (A in regs); aliasing legal from here

    const float* e2g = e2 + wave * 256 + mm;   // e2 for code group c: e2g[c*16]
    const unsigned short* gB = cbbf + (size_t)(wave * 256 + mm) * VQ_D + quad * 8;
    char* Bw = (char*)&Blds[wave][0][0];       // wave-private 8KB (2 x 4KB)

    // ---- phase 1: x2-free score min, LDS-pipelined B ----
    float bmin[16];
    #pragma unroll
    for (int i = 0; i < 16; ++i) bmin[i] = 1e30f;

    VQ_PF(0, 0)
    #pragma unroll 1
    for (int c = 0; c < 16; ++c) {
        const int sb = c & 1;
        asm volatile("s_waitcnt vmcnt(0)" ::: "memory");
        __builtin_amdgcn_sched_barrier(0);
        short8 B[4];
        VQ_RDB(B, sb)
        if (c < 15) VQ_PF(sb ^ 1, c + 1)         // overlaps MFMA+epilogue
        const float e2c = e2g[c * 16];
        VQ_MFMA(B)
        #pragma unroll
        for (int p = 0; p < 4; ++p)
            #pragma unroll
            for (int r = 0; r < 4; ++r) {
                const float s = fmaf(-2.0f, Cm[p][r], e2c);
                bmin[p * 4 + r] = fminf(bmin[p * 4 + r], s);
            }
    }

    // reduce min across the 16 lanes of each quad-group (code dimension)
    #pragma unroll
    for (int i = 0; i < 16; ++i) {
        float v = bmin[i];
        v = fminf(v, __shfl_xor(v, 1));
        v = fminf(v, __shfl_xor(v, 2));
        v = fminf(v, __shfl_xor(v, 4));
        v = fminf(v, __shfl_xor(v, 8));
        bmin[i] = v;
    }
    if (mm == 0) {
        #pragma unroll
        for (int p = 0; p < 4; ++p)
            #pragma unroll
            for (int r = 0; r < 4; ++r)
                bfminw[wave][p * 16 + quad * 4 + r] = bmin[p * 4 + r];
    }
    __syncthreads();
    if (tid < 64) {
        const float mn = fminf(fminf(bfminw[0][tid], bfminw[1][tid]),
                               fminf(bfminw[2][tid], bfminw[3][tid]));
        const float M = 2.0e-4f * sqrtf(x2s[tid]) + 2.5e-4f;
        threshs[tid] = mn + 2.0f * M;
    }
    __syncthreads();   // bfminw dead; cand writes may begin

    float thr[16];
    #pragma unroll
    for (int p = 0; p < 4; ++p)
        #pragma unroll
        for (int r = 0; r < 4; ++r)
            thr[p * 4 + r] = threshs[p * 16 + quad * 4 + r];

    // ---- phase 2: recompute s', collect candidates (same pipeline) ----
    VQ_PF(0, 0)
    #pragma unroll 1
    for (int c = 0; c < 16; ++c) {
        const int sb = c & 1;
        asm volatile("s_waitcnt vmcnt(0)" ::: "memory");
        __builtin_amdgcn_sched_barrier(0);
        short8 B[4];
        VQ_RDB(B, sb)
        if (c < 15) VQ_PF(sb ^ 1, c + 1)
        const float e2c = e2g[c * 16];
        VQ_MFMA(B)
        #pragma unroll
        for (int p = 0; p < 4; ++p)
            #pragma unroll
            for (int r = 0; r < 4; ++r) {
                const float s = fmaf(-2.0f, Cm[p][r], e2c);
                if (s <= thr[p * 4 + r]) {
                    const int idx = atomicAdd(&ncand, 1);
                    if (idx < CAND_CAP) {
                        const int px   = p * 16 + quad * 4 + r;
                        const int code = wave * 256 + c * 16 + mm;
                        cand[idx] = ((unsigned)px << 16) | (unsigned)code;
                    }
                }
            }
    }
    __syncthreads();

    // ---- rescue: exact fp32 serial chain on candidates, one per lane.
    //      x from GLOBAL: the block's 32KB px-tile footprint is L2-hot.
    const int nc = ncand < CAND_CAP ? ncand : CAND_CAP;
    for (int i = tid; i < nc; i += 256) {
        const unsigned pc = cand[i];
        const int px = (int)(pc >> 16);
        const int k  = (int)(pc & 0xFFFFu);
        const float* crow = cb + (size_t)k * VQ_D;
        float dot = 0.f;
        #pragma unroll
        for (int q = 0; q < 32; ++q) {
            const float4 cv = *(const float4*)(crow + q * 4);
            dot = fmaf(xg[(size_t)(q * 4 + 0) * VQ_HW + px], cv.x, dot);
            dot = fmaf(xg[(size_t)(q * 4 + 1) * VQ_HW + px], cv.y, dot);
            dot = fmaf(xg[(size_t)(q * 4 + 2) * VQ_HW + px], cv.z, dot);
            dot = fmaf(xg[(size_t)(q * 4 + 3) * VQ_HW + px], cv.w, dot);
        }
        const float t3 = (x2s[px] - 2.0f * dot) + e2[k];
        const unsigned long long key =
            ((unsigned long long)__float_as_uint(t3) << 32) | (unsigned)k;
        atomicMin(&fkey[px], key);
    }
    __syncthreads();

    // ---- writeback: vectorized codebook reads, nontemporal out stores ----
    {
        const int px = tid & 63;
        const int dh = tid >> 6;
        const int fb = (int)(fkey[px] & 0xFFFFFFFFULL);
        const float* crow = cb + (size_t)fb * VQ_D + dh * 32;
        float* og = out + (size_t)b * VQ_D * VQ_HW + hw0;
        #pragma unroll
        for (int j = 0; j < 8; ++j) {
            const float4 cv = *(const float4*)(crow + j * 4);
            const int d = dh * 32 + j * 4;
            __builtin_nontemporal_store(cv.x, &og[(size_t)(d + 0) * VQ_HW + px]);
            __builtin_nontemporal_store(cv.y, &og[(size_t)(d + 1) * VQ_HW + px]);
            __builtin_nontemporal_store(cv.z, &og[(size_t)(d + 2) * VQ_HW + px]);
            __builtin_nontemporal_store(cv.w, &og[(size_t)(d + 3) * VQ_HW + px]);
        }
    }
}

extern "C" void kernel_launch(void* const* d_in, const int* in_sizes, int n_in,
                              void* d_out, int out_size, void* d_ws, size_t ws_size,
                              hipStream_t stream) {
    const float* latents = (const float*)d_in[0];
    const float* cb      = (const float*)d_in[1];
    unsigned short* cbbf = (unsigned short*)d_ws;              // 256 KB
    float* e2            = (float*)((char*)d_ws + 262144);     // 4 KB
    float* out           = (float*)d_out;

    vq_prep_kernel<<<dim3(32), dim3(256), 0, stream>>>(cb, cbbf, e2);
    vq_main_kernel<<<dim3(1024), dim3(256), 0, stream>>>(latents, cb, cbbf, e2, out);
}